// Round 1
// baseline (173.955 us; speedup 1.0000x reference)
//
#include <hip/hip_runtime.h>
#include <math.h>

// Problem shape (fixed by setup_inputs)
#define BATCH 32
#define HH 768
#define WW 768
#define NBLK 512            // 32 b x 8 ri x 2 halves  (each block: 4 row-chunks)
#define NREG 2048           // level-3 regions: 32 b x 8 ri x 8 rj
#define CHUNK_FLOATS (12 * WW)

typedef float v4f __attribute__((ext_vector_type(4)));

// ---------------------------------------------------------------------------
// Kernel 1: block = (b, ri, half) covering 48 full-width rows = 4 chunks of 12.
// 32-lane group g owns column stripe g (96 floats) of each chunk.
// Double-buffered register pipeline: issue chunk j+1's 18 global_load_dwordx4
// while consuming chunk j; counted s_waitcnt vmcnt(18) keeps 18-36 loads in
// flight per wave continuously (never a full drain until the epilogue).
// Grid = 512 blocks -> 2 blocks/CU fully resident, no mid-kernel re-dispatch.
// ---------------------------------------------------------------------------
__global__ __launch_bounds__(256) void region_reduce(
    const float* __restrict__ pred, const float* __restrict__ gt,
    float* __restrict__ sq_out, float* __restrict__ dws)
{
    const int bid  = blockIdx.x;      // b*16 + ri*2 + half
    const int b    = bid >> 4;
    const int ri   = (bid >> 1) & 7;
    const int half = bid & 1;
    const size_t base = (size_t)b * (HH * WW) + (size_t)(ri * 96 + half * 48) * WW;

    const int t = threadIdx.x;
    const int g = t >> 5;       // column stripe 0..7
    const int l = t & 31;

    const float* pb = pred + base;   // block-uniform -> SGPR pair
    const float* gb = gt   + base;

    // stripe = 12 rows x 24 float4; lane l handles q = l + 32k, k=0..8
    unsigned off[9];
    #pragma unroll
    for (int k = 0; k < 9; ++k) {
        const int q   = l + 32 * k;          // 0..287
        const int row = q / 24;
        const int c   = q - row * 24;
        off[k] = (unsigned)((g * 96 + row * WW + c * 4) * sizeof(float));
    }

    v4f pA[9], qA[9], pB[9], qB[9];
    float sq = 0.f, ds0, ds1, ds2, ds3;

#define ISSUE(P, Q, PP, GG)                                                   \
    do {                                                                      \
        _Pragma("unroll")                                                     \
        for (int k = 0; k < 9; ++k)                                           \
            asm volatile("global_load_dwordx4 %0, %1, %2"                     \
                         : "=&v"((P)[k]) : "v"(off[k]), "s"(PP));             \
        _Pragma("unroll")                                                     \
        for (int k = 0; k < 9; ++k)                                           \
            asm volatile("global_load_dwordx4 %0, %1, %2"                     \
                         : "=&v"((Q)[k]) : "v"(off[k]), "s"(GG));             \
    } while (0)

// Counted wait: after this, (P,Q)'s 18 loads (the oldest outstanding) are
// complete; the "+v" ties force every consumer to stay after the wait.
#define TIE18(P, Q, N)                                                        \
    asm volatile("s_waitcnt vmcnt(" N ")"                                     \
                 : "+v"((P)[0]), "+v"((P)[1]), "+v"((P)[2]), "+v"((P)[3]),    \
                   "+v"((P)[4]), "+v"((P)[5]), "+v"((P)[6]), "+v"((P)[7]),    \
                   "+v"((P)[8]),                                              \
                   "+v"((Q)[0]), "+v"((Q)[1]), "+v"((Q)[2]), "+v"((Q)[3]),    \
                   "+v"((Q)[4]), "+v"((Q)[5]), "+v"((Q)[6]), "+v"((Q)[7]),    \
                   "+v"((Q)[8])                                               \
                 :: "memory")

#define CONSUME(P, Q, DS)                                                     \
    do {                                                                      \
        float lds_ = 0.f, lsq_ = 0.f;                                         \
        _Pragma("unroll")                                                     \
        for (int k = 0; k < 9; ++k) {                                         \
            const float dx = (P)[k][0] - (Q)[k][0];                           \
            const float dy = (P)[k][1] - (Q)[k][1];                           \
            const float dz = (P)[k][2] - (Q)[k][2];                           \
            const float dw = (P)[k][3] - (Q)[k][3];                           \
            lsq_ += (dx * dx + dy * dy) + (dz * dz + dw * dw);                \
            lds_ += (dx + dy) + (dz + dw);                                    \
        }                                                                     \
        sq += lsq_;                                                           \
        (DS) = lds_;                                                          \
    } while (0)

    // 4-chunk ping-pong. Outstanding-load ledger (volatile asm stays in order):
    //   A0(18) B1(36) | wait18 -> A0 done | A2(36) | wait18 -> B1 done |
    //   B3(36) | wait18 -> A2 done | wait0 -> B3 done
    ISSUE(pA, qA, pb, gb);
    ISSUE(pB, qB, pb + CHUNK_FLOATS, gb + CHUNK_FLOATS);
    TIE18(pA, qA, "18");
    CONSUME(pA, qA, ds0);
    ISSUE(pA, qA, pb + 2 * CHUNK_FLOATS, gb + 2 * CHUNK_FLOATS);
    TIE18(pB, qB, "18");
    CONSUME(pB, qB, ds1);
    ISSUE(pB, qB, pb + 3 * CHUNK_FLOATS, gb + 3 * CHUNK_FLOATS);
    TIE18(pA, qA, "18");
    CONSUME(pA, qA, ds2);
    TIE18(pB, qB, "0");
    CONSUME(pB, qB, ds3);

#undef ISSUE
#undef TIE18
#undef CONSUME

    // ds0..3: reduce within the 32-lane group (stripe-local).
    // Tree for lane 0 / lane 32 only pulls from its own 32-lane half.
    #pragma unroll
    for (int off_ = 16; off_ > 0; off_ >>= 1) {
        ds0 += __shfl_down(ds0, off_, 64);
        ds1 += __shfl_down(ds1, off_, 64);
        ds2 += __shfl_down(ds2, off_, 64);
        ds3 += __shfl_down(ds3, off_, 64);
    }
    // sq: reduce across the full 64-lane wave
    #pragma unroll
    for (int off_ = 32; off_ > 0; off_ >>= 1) sq += __shfl_down(sq, off_, 64);

    if (l == 0) {
        // dws[region*8 + chunk], chunk = half*4 + j  -> 16B-aligned float4
        float4* dp = (float4*)(dws + (((((b << 3) + ri) << 3) + g) << 3) + (half << 2));
        *dp = make_float4(ds0, ds1, ds2, ds3);
    }

    __shared__ float lsq[4];
    const int wave = t >> 6;
    if ((t & 63) == 0) lsq[wave] = sq;
    __syncthreads();
    if (t == 0) sq_out[bid] = (lsq[0] + lsq[1]) + (lsq[2] + lsq[3]);
}

// ---------------------------------------------------------------------------
// Kernel 2: single block. Aggregates chunk partials -> level-3 regions,
// builds levels 2/1, count loss, domain CE, final weighted sum.
// ---------------------------------------------------------------------------
__global__ __launch_bounds__(256) void finalize(
    const float* __restrict__ sq, const float* __restrict__ dws,
    const float* __restrict__ rgb, const float* __restrict__ th,
    float* __restrict__ out)
{
    __shared__ float d[NREG];        // level-3 region diffs (b*64 + ri*8 + rj)
    __shared__ float d2[BATCH * 16];
    __shared__ float d1[BATCH * 4];
    __shared__ float redbuf[4 * 6];
    const int t = threadIdx.x;

    // density partials (512 floats as 128 float4)
    float s_sq = 0.f;
    if (t < NBLK / 4) {
        const float4 v = ((const float4*)sq)[t];
        s_sq = (v.x + v.y) + (v.z + v.w);
    }

    // level-3 region diffs: sum 8 chunk partials each
    float l3 = 0.f;
    #pragma unroll
    for (int k = 0; k < 8; ++k) {
        const int r = t + 256 * k;
        const float4* dp = (const float4*)(dws + r * 8);
        const float4 a = dp[0], bb = dp[1];
        const float v = ((a.x + a.y) + (a.z + a.w)) + ((bb.x + bb.y) + (bb.z + bb.w));
        d[r] = v;
        l3 += fabsf(v);
    }
    __syncthreads();

    // level 2: 32 batches x 16 cells, 2x2 aggregation of level-3
    float l2 = 0.f;
    #pragma unroll
    for (int k = 0; k < 2; ++k) {
        const int i = t + 256 * k;
        const int b = i >> 4, r2 = i & 15;
        const int i2 = r2 >> 2, j2 = r2 & 3;
        const float* db = d + b * 64;
        const float v = (db[(2 * i2) * 8 + 2 * j2]     + db[(2 * i2) * 8 + 2 * j2 + 1])
                      + (db[(2 * i2 + 1) * 8 + 2 * j2] + db[(2 * i2 + 1) * 8 + 2 * j2 + 1]);
        d2[i] = v;
        l2 += fabsf(v);
    }
    __syncthreads();

    // level 1: 32 x 4 cells
    float l1 = 0.f;
    if (t < BATCH * 4) {
        const int b = t >> 2, r1 = t & 3;
        const int i1 = r1 >> 1, j1 = r1 & 1;
        const float* db = d2 + b * 16;
        const float v = (db[(2 * i1) * 4 + 2 * j1]     + db[(2 * i1) * 4 + 2 * j1 + 1])
                      + (db[(2 * i1 + 1) * 4 + 2 * j1] + db[(2 * i1 + 1) * 4 + 2 * j1 + 1]);
        d1[t] = v;
        l1 = fabsf(v);
    }
    __syncthreads();

    // per-batch count diff + domain CE
    float cnt = 0.f, dom = 0.f;
    if (t < BATCH) {
        const float c = (d1[t * 4] + d1[t * 4 + 1]) + (d1[t * 4 + 2] + d1[t * 4 + 3]);
        cnt = fabsf(c);
        const float x0 = rgb[t * 2], x1 = rgb[t * 2 + 1];
        const float mx = fmaxf(x0, x1);
        dom  = (mx + logf(expf(x0 - mx) + expf(x1 - mx))) - x0;
        const float y0 = th[t * 2], y1 = th[t * 2 + 1];
        const float my = fmaxf(y0, y1);
        dom += (my + logf(expf(y0 - my) + expf(y1 - my))) - y1;
    }

    // fused 6-value reduction: wave shuffle, then 4-wave LDS combine
    float vals[6] = {s_sq, l3, l2, l1, cnt, dom};
    #pragma unroll
    for (int off = 32; off > 0; off >>= 1) {
        #pragma unroll
        for (int j = 0; j < 6; ++j) vals[j] += __shfl_down(vals[j], off, 64);
    }
    const int wave = t >> 6;
    if ((t & 63) == 0) {
        #pragma unroll
        for (int j = 0; j < 6; ++j) redbuf[wave * 6 + j] = vals[j];
    }
    __syncthreads();
    if (t == 0) {
        float S[6];
        #pragma unroll
        for (int j = 0; j < 6; ++j)
            S[j] = (redbuf[j] + redbuf[6 + j]) + (redbuf[12 + j] + redbuf[18 + j]);
        const float density  = S[0] / (float)((size_t)BATCH * HH * WW);
        const float count_l  = S[4] / (float)BATCH;
        const float regional = ((S[3] + S[2] + S[1]) / (float)BATCH) / 192.0f;
        const float domain   = S[5] / 64.0f;
        out[0] = 100.0f * density + 0.001f * count_l + 1.0f * regional + 0.5f * domain;
    }
}

extern "C" void kernel_launch(void* const* d_in, const int* in_sizes, int n_in,
                              void* d_out, int out_size, void* d_ws, size_t ws_size,
                              hipStream_t stream) {
    const float* pred = (const float*)d_in[0];
    const float* gt   = (const float*)d_in[1];
    const float* rgb  = (const float*)d_in[2];
    const float* th   = (const float*)d_in[3];
    float* out = (float*)d_out;

    float* sq  = (float*)d_ws;         // [512]
    float* dws = sq + NBLK;            // [2048 * 8] chunk partials

    region_reduce<<<NBLK, 256, 0, stream>>>(pred, gt, sq, dws);
    finalize<<<1, 256, 0, stream>>>(sq, dws, rgb, th, out);
}

// Round 2
// 171.832 us; speedup vs baseline: 1.0124x; 1.0124x over previous
//
#include <hip/hip_runtime.h>
#include <math.h>

// Problem shape (fixed by setup_inputs)
#define BATCH 32
#define HH 768
#define WW 768
#define NBLK 2048   // 32 batches x 8 region-rows x 8 row-chunks

typedef float v4f __attribute__((ext_vector_type(4)));

// ---------------------------------------------------------------------------
// Kernel 1: block = (b, ri, chunk) covering 12 full-width rows (36 KB span).
// Pure lane-contiguous addressing: instruction (wave w, slot k) loads the
// 1-KB float4 group (w*9+k)*64 + lane  -- the m13-copy access pattern.
// The gt stream is SKEWED by 4 slots: gt slot k fetches group (k+4)%9 of the
// wave's window, so co-issued pred/gt loads are +-4-5 KB apart (different
// HBM channel / DRAM bank / L2 set under any <=4KB interleave) instead of
// low-bit-identical. The skew is undone at consume by a compile-time
// register permutation: q4[k] pairs with p[(k+4)%9].
// ---------------------------------------------------------------------------
__global__ __launch_bounds__(256) void region_reduce(
    const float* __restrict__ pred, const float* __restrict__ gt,
    float* __restrict__ sq_out, float* __restrict__ dws)
{
    const int bid   = blockIdx.x;        // b*64 + ri*8 + chunk
    const int b     = bid >> 6;
    const int ri    = (bid >> 3) & 7;
    const int chunk = bid & 7;
    const size_t base = (size_t)b * (HH * WW) + (size_t)(ri * 96 + chunk * 12) * WW;

    const int t = threadIdx.x;
    const int w = t >> 6;       // wave 0..3
    const int l = t & 63;

    const float* pb = pred + base;   // block-uniform -> SGPR pair
    const float* gb = gt   + base;

    // float4 element for (w, slot k, lane l): m = (w*9+k)*64 + l   (m in [0,2304))
    unsigned offp[9], offg[9];
    #pragma unroll
    for (int k = 0; k < 9; ++k) {
        offp[k] = (unsigned)(((w * 9 + k) * 64 + l) * 16);
        offg[k] = (unsigned)(((w * 9 + ((k + 4) % 9)) * 64 + l) * 16);
    }

    v4f p[9], q4[9];
    #pragma unroll
    for (int k = 0; k < 9; ++k)
        asm volatile("global_load_dwordx4 %0, %1, %2"
                     : "=&v"(p[k]) : "v"(offp[k]), "s"(pb));
    #pragma unroll
    for (int k = 0; k < 9; ++k)
        asm volatile("global_load_dwordx4 %0, %1, %2"
                     : "=&v"(q4[k]) : "v"(offg[k]), "s"(gb));
    // One wait for all 18; "+v" ties force every use to stay after it.
    asm volatile("s_waitcnt vmcnt(0)"
                 : "+v"(p[0]), "+v"(p[1]), "+v"(p[2]), "+v"(p[3]), "+v"(p[4]),
                   "+v"(p[5]), "+v"(p[6]), "+v"(p[7]), "+v"(p[8]),
                   "+v"(q4[0]), "+v"(q4[1]), "+v"(q4[2]), "+v"(q4[3]), "+v"(q4[4]),
                   "+v"(q4[5]), "+v"(q4[6]), "+v"(q4[7]), "+v"(q4[8])
                 :: "memory");

    // consume: q4[k] holds gt of slot j=(k+4)%9 -> pairs with p[j].
    // element m = (w*9+j)*64+l -> col4 c = 64*(j%3)+l -> region col rj = c/24.
    float sq = 0.f, ds0 = 0.f, ds1 = 0.f, ds2 = 0.f;
    #pragma unroll
    for (int k = 0; k < 9; ++k) {
        const int j = (k + 4) % 9;       // compile-time
        const float dx = p[j][0] - q4[k][0];
        const float dy = p[j][1] - q4[k][1];
        const float dz = p[j][2] - q4[k][2];
        const float dw = p[j][3] - q4[k][3];
        sq += (dx * dx + dy * dy) + (dz * dz + dw * dw);
        const float s = (dx + dy) + (dz + dw);
        if (j % 3 == 0)      ds0 += s;   // folds at compile time
        else if (j % 3 == 1) ds1 += s;
        else                 ds2 += s;
    }

    // regional bins: bucket i covers col4 c = 64*i + l  ->  rj = (64*i+l)/24
    __shared__ float bins[8];
    __shared__ float lsq[4];
    if (t < 8) bins[t] = 0.f;
    __syncthreads();
    atomicAdd(&bins[l / 24],         ds0);
    atomicAdd(&bins[(64 + l) / 24],  ds1);
    atomicAdd(&bins[(128 + l) / 24], ds2);

    // sq: reduce across the full 64-lane wave
    #pragma unroll
    for (int off_ = 32; off_ > 0; off_ >>= 1) sq += __shfl_down(sq, off_, 64);
    if (l == 0) lsq[w] = sq;
    __syncthreads();

    if (t < 8)
        dws[((((b << 3) + ri) << 3) + t) * 8 + chunk] = bins[t];
    if (t == 0) sq_out[bid] = (lsq[0] + lsq[1]) + (lsq[2] + lsq[3]);
}

// ---------------------------------------------------------------------------
// Kernel 2: single block. Aggregates chunk partials -> level-3 regions,
// builds levels 2/1, count loss, domain CE, final weighted sum.
// ---------------------------------------------------------------------------
__global__ __launch_bounds__(256) void finalize(
    const float* __restrict__ sq, const float* __restrict__ dws,
    const float* __restrict__ rgb, const float* __restrict__ th,
    float* __restrict__ out)
{
    __shared__ float d[NBLK];        // level-3 region diffs (b*64 + ri*8 + rj)
    __shared__ float d2[BATCH * 16];
    __shared__ float d1[BATCH * 4];
    __shared__ float redbuf[4 * 6];
    const int t = threadIdx.x;

    // density partials (2048 floats as 512 float4)
    float s_sq = 0.f;
    const float4* sq4 = (const float4*)sq;
    #pragma unroll
    for (int k = 0; k < 2; ++k) {
        const float4 v = sq4[t + 256 * k];
        s_sq += (v.x + v.y) + (v.z + v.w);
    }

    // level-3 region diffs: sum 8 chunk partials each
    float l3 = 0.f;
    #pragma unroll
    for (int k = 0; k < 8; ++k) {
        const int r = t + 256 * k;
        const float4* dp = (const float4*)(dws + r * 8);
        const float4 a = dp[0], bb = dp[1];
        const float v = ((a.x + a.y) + (a.z + a.w)) + ((bb.x + bb.y) + (bb.z + bb.w));
        d[r] = v;
        l3 += fabsf(v);
    }
    __syncthreads();

    // level 2: 32 batches x 16 cells, 2x2 aggregation of level-3
    float l2 = 0.f;
    #pragma unroll
    for (int k = 0; k < 2; ++k) {
        const int i = t + 256 * k;
        const int b = i >> 4, r2 = i & 15;
        const int i2 = r2 >> 2, j2 = r2 & 3;
        const float* db = d + b * 64;
        const float v = (db[(2 * i2) * 8 + 2 * j2]     + db[(2 * i2) * 8 + 2 * j2 + 1])
                      + (db[(2 * i2 + 1) * 8 + 2 * j2] + db[(2 * i2 + 1) * 8 + 2 * j2 + 1]);
        d2[i] = v;
        l2 += fabsf(v);
    }
    __syncthreads();

    // level 1: 32 x 4 cells
    float l1 = 0.f;
    if (t < BATCH * 4) {
        const int b = t >> 2, r1 = t & 3;
        const int i1 = r1 >> 1, j1 = r1 & 1;
        const float* db = d2 + b * 16;
        const float v = (db[(2 * i1) * 4 + 2 * j1]     + db[(2 * i1) * 4 + 2 * j1 + 1])
                      + (db[(2 * i1 + 1) * 4 + 2 * j1] + db[(2 * i1 + 1) * 4 + 2 * j1 + 1]);
        d1[t] = v;
        l1 = fabsf(v);
    }
    __syncthreads();

    // per-batch count diff + domain CE
    float cnt = 0.f, dom = 0.f;
    if (t < BATCH) {
        const float c = (d1[t * 4] + d1[t * 4 + 1]) + (d1[t * 4 + 2] + d1[t * 4 + 3]);
        cnt = fabsf(c);
        const float x0 = rgb[t * 2], x1 = rgb[t * 2 + 1];
        const float mx = fmaxf(x0, x1);
        dom  = (mx + logf(expf(x0 - mx) + expf(x1 - mx))) - x0;
        const float y0 = th[t * 2], y1 = th[t * 2 + 1];
        const float my = fmaxf(y0, y1);
        dom += (my + logf(expf(y0 - my) + expf(y1 - my))) - y1;
    }

    // fused 6-value reduction: wave shuffle, then 4-wave LDS combine
    float vals[6] = {s_sq, l3, l2, l1, cnt, dom};
    #pragma unroll
    for (int off = 32; off > 0; off >>= 1) {
        #pragma unroll
        for (int j = 0; j < 6; ++j) vals[j] += __shfl_down(vals[j], off, 64);
    }
    const int wave = t >> 6;
    if ((t & 63) == 0) {
        #pragma unroll
        for (int j = 0; j < 6; ++j) redbuf[wave * 6 + j] = vals[j];
    }
    __syncthreads();
    if (t == 0) {
        float S[6];
        #pragma unroll
        for (int j = 0; j < 6; ++j)
            S[j] = (redbuf[j] + redbuf[6 + j]) + (redbuf[12 + j] + redbuf[18 + j]);
        const float density  = S[0] / (float)((size_t)BATCH * HH * WW);
        const float count_l  = S[4] / (float)BATCH;
        const float regional = ((S[3] + S[2] + S[1]) / (float)BATCH) / 192.0f;
        const float domain   = S[5] / 64.0f;
        out[0] = 100.0f * density + 0.001f * count_l + 1.0f * regional + 0.5f * domain;
    }
}

extern "C" void kernel_launch(void* const* d_in, const int* in_sizes, int n_in,
                              void* d_out, int out_size, void* d_ws, size_t ws_size,
                              hipStream_t stream) {
    const float* pred = (const float*)d_in[0];
    const float* gt   = (const float*)d_in[1];
    const float* rgb  = (const float*)d_in[2];
    const float* th   = (const float*)d_in[3];
    float* out = (float*)d_out;

    float* sq  = (float*)d_ws;         // [2048]
    float* dws = sq + NBLK;            // [2048 * 8] chunk partials

    region_reduce<<<NBLK, 256, 0, stream>>>(pred, gt, sq, dws);
    finalize<<<1, 256, 0, stream>>>(sq, dws, rgb, th, out);
}

// Round 3
// 158.360 us; speedup vs baseline: 1.0985x; 1.0851x over previous
//
#include <hip/hip_runtime.h>
#include <math.h>

// Problem shape (fixed by setup_inputs)
#define BATCH 32
#define HH 768
#define WW 768
#define NBLK 2048   // 32 batches x 8 region-rows x 8 row-chunks

typedef float v4f __attribute__((ext_vector_type(4)));

// ---------------------------------------------------------------------------
// Kernel 1: block = (b, ri, chunk) covering 12 full-width rows (36 KB span).
// Lane-contiguous addressing: load (wave w, slot k) covers the 1-KB float4
// group (w*9+k)*64 + lane. All loads are NON-TEMPORAL (nt flag): streaming
// hint so the 147.5 MB dual stream bypasses/evicts-first in L2/MALL instead
// of being throttled by the cache hit-service path (the 2.7 TB/s invariant
// observed across rounds 0-2).
// ---------------------------------------------------------------------------
__global__ __launch_bounds__(256) void region_reduce(
    const float* __restrict__ pred, const float* __restrict__ gt,
    float* __restrict__ sq_out, float* __restrict__ dws)
{
    const int bid   = blockIdx.x;        // b*64 + ri*8 + chunk
    const int b     = bid >> 6;
    const int ri    = (bid >> 3) & 7;
    const int chunk = bid & 7;
    const size_t base = (size_t)b * (HH * WW) + (size_t)(ri * 96 + chunk * 12) * WW;

    const int t = threadIdx.x;
    const int w = t >> 6;       // wave 0..3
    const int l = t & 63;

    // float4 element for (w, slot k, lane l): m = (w*9+k)*64 + l   (m in [0,2304))
    const v4f* pp = (const v4f*)(pred + base) + (w * 9) * 64 + l;
    const v4f* gp = (const v4f*)(gt   + base) + (w * 9) * 64 + l;

    v4f p[9], q4[9];
    #pragma unroll
    for (int k = 0; k < 9; ++k) p[k]  = __builtin_nontemporal_load(pp + k * 64);
    #pragma unroll
    for (int k = 0; k < 9; ++k) q4[k] = __builtin_nontemporal_load(gp + k * 64);

    // consume: element m = (w*9+k)*64+l -> col4 c = 64*(k%3)+l -> rj = c/24.
    float sq = 0.f, ds0 = 0.f, ds1 = 0.f, ds2 = 0.f;
    #pragma unroll
    for (int k = 0; k < 9; ++k) {
        const float dx = p[k][0] - q4[k][0];
        const float dy = p[k][1] - q4[k][1];
        const float dz = p[k][2] - q4[k][2];
        const float dw = p[k][3] - q4[k][3];
        sq += (dx * dx + dy * dy) + (dz * dz + dw * dw);
        const float s = (dx + dy) + (dz + dw);
        if (k % 3 == 0)      ds0 += s;   // folds at compile time
        else if (k % 3 == 1) ds1 += s;
        else                 ds2 += s;
    }

    // regional bins: bucket i covers col4 c = 64*i + l  ->  rj = (64*i+l)/24
    __shared__ float bins[8];
    __shared__ float lsq[4];
    if (t < 8) bins[t] = 0.f;
    __syncthreads();
    atomicAdd(&bins[l / 24],         ds0);
    atomicAdd(&bins[(64 + l) / 24],  ds1);
    atomicAdd(&bins[(128 + l) / 24], ds2);

    // sq: reduce across the full 64-lane wave
    #pragma unroll
    for (int off_ = 32; off_ > 0; off_ >>= 1) sq += __shfl_down(sq, off_, 64);
    if (l == 0) lsq[w] = sq;
    __syncthreads();

    if (t < 8)
        dws[((((b << 3) + ri) << 3) + t) * 8 + chunk] = bins[t];
    if (t == 0) sq_out[bid] = (lsq[0] + lsq[1]) + (lsq[2] + lsq[3]);
}

// ---------------------------------------------------------------------------
// Kernel 2: single block. Aggregates chunk partials -> level-3 regions,
// builds levels 2/1, count loss, domain CE, final weighted sum.
// ---------------------------------------------------------------------------
__global__ __launch_bounds__(256) void finalize(
    const float* __restrict__ sq, const float* __restrict__ dws,
    const float* __restrict__ rgb, const float* __restrict__ th,
    float* __restrict__ out)
{
    __shared__ float d[NBLK];        // level-3 region diffs (b*64 + ri*8 + rj)
    __shared__ float d2[BATCH * 16];
    __shared__ float d1[BATCH * 4];
    __shared__ float redbuf[4 * 6];
    const int t = threadIdx.x;

    // density partials (2048 floats as 512 float4)
    float s_sq = 0.f;
    const float4* sq4 = (const float4*)sq;
    #pragma unroll
    for (int k = 0; k < 2; ++k) {
        const float4 v = sq4[t + 256 * k];
        s_sq += (v.x + v.y) + (v.z + v.w);
    }

    // level-3 region diffs: sum 8 chunk partials each
    float l3 = 0.f;
    #pragma unroll
    for (int k = 0; k < 8; ++k) {
        const int r = t + 256 * k;
        const float4* dp = (const float4*)(dws + r * 8);
        const float4 a = dp[0], bb = dp[1];
        const float v = ((a.x + a.y) + (a.z + a.w)) + ((bb.x + bb.y) + (bb.z + bb.w));
        d[r] = v;
        l3 += fabsf(v);
    }
    __syncthreads();

    // level 2: 32 batches x 16 cells, 2x2 aggregation of level-3
    float l2 = 0.f;
    #pragma unroll
    for (int k = 0; k < 2; ++k) {
        const int i = t + 256 * k;
        const int b = i >> 4, r2 = i & 15;
        const int i2 = r2 >> 2, j2 = r2 & 3;
        const float* db = d + b * 64;
        const float v = (db[(2 * i2) * 8 + 2 * j2]     + db[(2 * i2) * 8 + 2 * j2 + 1])
                      + (db[(2 * i2 + 1) * 8 + 2 * j2] + db[(2 * i2 + 1) * 8 + 2 * j2 + 1]);
        d2[i] = v;
        l2 += fabsf(v);
    }
    __syncthreads();

    // level 1: 32 x 4 cells
    float l1 = 0.f;
    if (t < BATCH * 4) {
        const int b = t >> 2, r1 = t & 3;
        const int i1 = r1 >> 1, j1 = r1 & 1;
        const float* db = d2 + b * 16;
        const float v = (db[(2 * i1) * 4 + 2 * j1]     + db[(2 * i1) * 4 + 2 * j1 + 1])
                      + (db[(2 * i1 + 1) * 4 + 2 * j1] + db[(2 * i1 + 1) * 4 + 2 * j1 + 1]);
        d1[t] = v;
        l1 = fabsf(v);
    }
    __syncthreads();

    // per-batch count diff + domain CE
    float cnt = 0.f, dom = 0.f;
    if (t < BATCH) {
        const float c = (d1[t * 4] + d1[t * 4 + 1]) + (d1[t * 4 + 2] + d1[t * 4 + 3]);
        cnt = fabsf(c);
        const float x0 = rgb[t * 2], x1 = rgb[t * 2 + 1];
        const float mx = fmaxf(x0, x1);
        dom  = (mx + logf(expf(x0 - mx) + expf(x1 - mx))) - x0;
        const float y0 = th[t * 2], y1 = th[t * 2 + 1];
        const float my = fmaxf(y0, y1);
        dom += (my + logf(expf(y0 - my) + expf(y1 - my))) - y1;
    }

    // fused 6-value reduction: wave shuffle, then 4-wave LDS combine
    float vals[6] = {s_sq, l3, l2, l1, cnt, dom};
    #pragma unroll
    for (int off = 32; off > 0; off >>= 1) {
        #pragma unroll
        for (int j = 0; j < 6; ++j) vals[j] += __shfl_down(vals[j], off, 64);
    }
    const int wave = t >> 6;
    if ((t & 63) == 0) {
        #pragma unroll
        for (int j = 0; j < 6; ++j) redbuf[wave * 6 + j] = vals[j];
    }
    __syncthreads();
    if (t == 0) {
        float S[6];
        #pragma unroll
        for (int j = 0; j < 6; ++j)
            S[j] = (redbuf[j] + redbuf[6 + j]) + (redbuf[12 + j] + redbuf[18 + j]);
        const float density  = S[0] / (float)((size_t)BATCH * HH * WW);
        const float count_l  = S[4] / (float)BATCH;
        const float regional = ((S[3] + S[2] + S[1]) / (float)BATCH) / 192.0f;
        const float domain   = S[5] / 64.0f;
        out[0] = 100.0f * density + 0.001f * count_l + 1.0f * regional + 0.5f * domain;
    }
}

extern "C" void kernel_launch(void* const* d_in, const int* in_sizes, int n_in,
                              void* d_out, int out_size, void* d_ws, size_t ws_size,
                              hipStream_t stream) {
    const float* pred = (const float*)d_in[0];
    const float* gt   = (const float*)d_in[1];
    const float* rgb  = (const float*)d_in[2];
    const float* th   = (const float*)d_in[3];
    float* out = (float*)d_out;

    float* sq  = (float*)d_ws;         // [2048]
    float* dws = sq + NBLK;            // [2048 * 8] chunk partials

    region_reduce<<<NBLK, 256, 0, stream>>>(pred, gt, sq, dws);
    finalize<<<1, 256, 0, stream>>>(sq, dws, rgb, th, out);
}